// Round 5
// baseline (74.548 us; speedup 1.0000x reference)
//
#include <hip/hip_runtime.h>
#include <hip/hip_bf16.h>
#include <hip/hip_fp16.h>

// ---------------- types / helpers ----------------
typedef __attribute__((ext_vector_type(8))) short bf16x8;     // MFMA A/B frag (4 VGPR)
typedef __attribute__((ext_vector_type(4))) float f32x4;      // MFMA C/D frag
typedef __attribute__((ext_vector_type(4))) unsigned int u32x4;
typedef __attribute__((ext_vector_type(2))) unsigned int u32x2;

#define MFMA_BF16(A,B,C) __builtin_amdgcn_mfma_f32_16x16x32_bf16((A),(B),(C),0,0,0)

static __device__ __forceinline__ unsigned int pkbf2(float a, float b) {
  __hip_bfloat162 h = __float22bfloat162_rn(make_float2(a, b));   // v_cvt_pk_bf16_f32
  unsigned int u; __builtin_memcpy(&u, &h, sizeof(u));
  return u;
}
static __device__ __forceinline__ unsigned short f2bf1(float f) {
  __hip_bfloat16 h = __float2bfloat16(f);
  unsigned short u; __builtin_memcpy(&u, &h, sizeof(u));
  return u;
}
// LDS 16B-unit swizzle hash (row bits 0..5 -> bank spread).
static __device__ __forceinline__ int swz8(int v) { return (v ^ (v >> 3)) & 7; }

// DPP row-rotate (within 16-lane row) — pure VALU, replaces ds_swizzle shuffles.
template<int N>
static __device__ __forceinline__ float rot16(float x) {
  return __builtin_bit_cast(float,
      __builtin_amdgcn_mov_dpp(__builtin_bit_cast(int, x), 0x120 + N, 0xF, 0xF, false));
}
// All-lane sum over the 16 lanes of a DPP row (lanes sharing lane>>4).
static __device__ __forceinline__ float sum16(float x) {
  x += rot16<8>(x);
  x += rot16<4>(x);
  x += rot16<2>(x);
  x += rot16<1>(x);
  return x;
}

// ---------------- d_ws layout (bytes) ----------------
// [    0,16384) : W_a1  bf16 B-frags [16 frag][64 lane][8 e]  frag f=kt*4+nt
// [16384,32768) : W_out bf16 B-frags same layout
// [32768,36864) : W_encT bf16 A-frags [4 mt][64 lane][8 e]  (k=8*(l>>4)+e, ch=16mt+(l&15); 0 for k>=9)
__global__ void gcn_prep(const float* __restrict__ wa1, const float* __restrict__ wout,
                         const float* __restrict__ wenc,
                         unsigned short* __restrict__ wa1f, unsigned short* __restrict__ woutf,
                         unsigned short* __restrict__ wencT) {
  int i = blockIdx.x * 512 + threadIdx.x;
  if (i < 8192) {
    int e = i & 7, l = (i >> 3) & 63, f = i >> 9;
    int kt = f >> 2, nt = f & 3;
    int k = 32 * kt + 8 * (l >> 4) + e;
    int col = 16 * nt + (l & 15);
    wa1f[i]  = f2bf1(wa1 [k * 64 + col]);
    woutf[i] = f2bf1(wout[k * 64 + col]);
  }
  int j = i - 8192;
  if (j >= 0 && j < 2048) {
    int e = j & 7, l = (j >> 3) & 63, mt = j >> 9;
    int k = 8 * (l >> 4) + e;
    int ch = 16 * mt + (l & 15);
    wencT[j] = (k < 9) ? f2bf1(wenc[k * 64 + ch]) : (unsigned short)0;
  }
}

// ---------------- fused main kernel ----------------
// 16 output rows / block, 128 threads (2 waves), grid 8192.
// LDS = 20480 B exactly -> 8 blocks/CU (163840/20480 = 8.0). 3 barriers total.
// LDS map (byte offsets):
//   [    0,18432) sE   [144 vec][64 ch] bf16; 16B units swizzled: unit = c8 ^ swz8(v)
//                 vec 0..127 = nbr, 128..143 = cur (row r at 128+r)
//   [18432,20480) sAgg [16 r][64 ch] bf16, swizzled like sE (written in G, read in O)
//                 sS[r] = 32 B f32 weights INSIDE sAgg row r at +((r&3)<<5):
//                 written in S, read at start of G (same wave as writer: r<8 <-> w0),
//                 then overwritten by the sAgg store (reads precede writes in-wave).
__global__ __launch_bounds__(128, 4) void gcn_main(
    const float* __restrict__ xcur, const float* __restrict__ xnbr,
    const int*   __restrict__ msk,
    const float* __restrict__ benc, const float* __restrict__ genc, const float* __restrict__ beenc,
    const float* __restrict__ ba1,  const float* __restrict__ wa2,
    const float* __restrict__ bout, const float* __restrict__ gout, const float* __restrict__ beout,
    const unsigned short* __restrict__ wa1f, const unsigned short* __restrict__ woutf,
    const unsigned short* __restrict__ wencT,
    float* __restrict__ out) {

  __shared__ __align__(16) char smem[20480];
  unsigned short* sE   = (unsigned short*)smem;
  unsigned short* sAgg = (unsigned short*)(smem + 18432);

  const int tid  = threadIdx.x;
  const int w    = tid >> 6;
  const int lane = tid & 63;
  const int lm   = lane & 15, g = lane >> 4;
  const int blk  = blockIdx.x;              // 16 output rows, 128 nbr vecs

  // Persisted across phases (prefetched early, used late):
  bf16x8 wf[16];                            // W_a1 frags (loaded before E->S barrier)
  bf16x8 wof[16];                           // W_out frags: [0..7] cur-half, [8..15] agg-half
  float bovv[4], gvo[4], bevo[4];
  float ba1v[4], wa2v[4];
  int4 mkv[4];                              // masks for this wave's 4 score tiles

  // ---------- Phase E: encode 144 vecs via transposed MFMA (D[ch][vec]) ----------
  {
    bf16x8 ef[4];
    #pragma unroll
    for (int mt = 0; mt < 4; mt++) ef[mt] = *(const bf16x8*)(wencT + (mt * 64 + lane) * 8);
    f32x4 bv[4], gv[4], bev[4];
    #pragma unroll
    for (int mt = 0; mt < 4; mt++) {
      bv[mt]  = *(const f32x4*)(benc  + 16 * mt + 4 * g);
      gv[mt]  = *(const f32x4*)(genc  + 16 * mt + 4 * g);
      bev[mt] = *(const f32x4*)(beenc + 16 * mt + 4 * g);
    }
    #pragma unroll
    for (int nt = 0; nt < 4; nt++) { ba1v[nt] = ba1[16 * nt + lm]; wa2v[nt] = wa2[16 * nt + lm]; }
    // 2-deep x prefetch pipeline over this wave's tiles: t = w, w+2, ... (<=8)
    float nx[8];
    {
      const float* xb = (w < 8) ? (xnbr + ((size_t)blk * 128 + w * 16 + lm) * 9)
                                : (xcur + ((size_t)blk * 16 + lm) * 9);
      #pragma unroll
      for (int e = 0; e < 8; e++) nx[e] = 0.f;
      if (g == 0) {
        #pragma unroll
        for (int e = 0; e < 8; e++) nx[e] = xb[e];
      } else if (g == 1) nx[0] = xb[8];
    }
    #pragma unroll
    for (int s5 = 0; s5 < 5; s5++) {
      int t = 2 * s5 + w;
      if (t > 8) break;
      float xv[8];
      #pragma unroll
      for (int e = 0; e < 8; e++) xv[e] = nx[e];
      int tn = t + 2;
      if (tn <= 8) {                        // issue next tile's loads now
        const float* xb = (tn < 8) ? (xnbr + ((size_t)blk * 128 + tn * 16 + lm) * 9)
                                   : (xcur + ((size_t)blk * 16 + lm) * 9);
        #pragma unroll
        for (int e = 0; e < 8; e++) nx[e] = 0.f;
        if (g == 0) {
          #pragma unroll
          for (int e = 0; e < 8; e++) nx[e] = xb[e];
        } else if (g == 1) nx[0] = xb[8];
      }
      int v = (t < 8) ? (t * 16 + lm) : (128 + lm);
      u32x4 bq;
      #pragma unroll
      for (int e2 = 0; e2 < 4; e2++) bq[e2] = pkbf2(xv[2 * e2], xv[2 * e2 + 1]);
      bf16x8 bfr = __builtin_bit_cast(bf16x8, bq);
      f32x4 acc[4];
      #pragma unroll
      for (int mt = 0; mt < 4; mt++) acc[mt] = bv[mt];   // bias folded into MFMA C
      #pragma unroll
      for (int mt = 0; mt < 4; mt++) acc[mt] = MFMA_BF16(ef[mt], bfr, acc[mt]);
      float s1 = 0.f, s2 = 0.f;
      #pragma unroll
      for (int mt = 0; mt < 4; mt++)
        #pragma unroll
        for (int i = 0; i < 4; i++) { float h = acc[mt][i]; s1 += h; s2 = fmaf(h, h, s2); }
      s1 += __shfl_xor(s1, 16); s1 += __shfl_xor(s1, 32);
      s2 += __shfl_xor(s2, 16); s2 += __shfl_xor(s2, 32);
      float mu = s1 * (1.f / 64.f);
      float rs = rsqrtf(s2 * (1.f / 64.f) - mu * mu + 1e-5f);
      float t0 = -mu * rs;                  // y = fma(fma(h, rs, t0), g, be): 3 ops/ch
      int h8 = swz8(v);
      #pragma unroll
      for (int mt = 0; mt < 4; mt++) {
        float y0 = fmaxf(fmaf(fmaf(acc[mt][0], rs, t0), gv[mt][0], bev[mt][0]), 0.f);
        float y1 = fmaxf(fmaf(fmaf(acc[mt][1], rs, t0), gv[mt][1], bev[mt][1]), 0.f);
        float y2 = fmaxf(fmaf(fmaf(acc[mt][2], rs, t0), gv[mt][2], bev[mt][2]), 0.f);
        float y3 = fmaxf(fmaf(fmaf(acc[mt][3], rs, t0), gv[mt][3], bev[mt][3]), 0.f);
        int unit = (2 * mt + (g >> 1)) ^ h8;
        *(u32x2*)&sE[v * 64 + unit * 8 + ((g & 1) << 2)] = u32x2{pkbf2(y0, y1), pkbf2(y2, y3)};
      }
    }
    // Prefetch phase-S operands so they are in flight across the barrier.
    #pragma unroll
    for (int f = 0; f < 16; f++) wf[f] = *(const bf16x8*)(wa1f + (f * 64 + lane) * 8);
    #pragma unroll
    for (int mm = 0; mm < 4; mm++) {
      int r2 = 8 * w + 2 * mm + (g >> 1);
      mkv[mm] = *(const int4*)(msk + ((size_t)(blk * 16 + r2)) * 8 + 4 * (g & 1));
    }
  }
  __syncthreads();

  // ---------- Phase S: scores + fused masked softmax -> sS weights ----------
  // hc dedup: cur@W_a1[0:64]+b_a1 is shared by all 8 neighbors of a row. Computed
  // ONCE per wave as a 16-row MFMA tile with pre-permuted A-rows so that lane
  // (g,lm)'s hca[nt][i] IS hc[8w + 2i + (g>>1)][16nt+lm] (score tile mm=i's init).
  {
    f32x4 hca[4];
    #pragma unroll
    for (int nt = 0; nt < 4; nt++)
      hca[nt] = f32x4{ba1v[nt], ba1v[nt], ba1v[nt], ba1v[nt]};
    {
      const int vcu = 128 + 8 * w + 2 * (lm & 3) + (lm >> 3), hcu = swz8(vcu);
      #pragma unroll
      for (int ks = 0; ks < 2; ks++) {                   // cur @ W_a1[0:64]
        bf16x8 a = *(const bf16x8*)&sE[vcu * 64 + (((4 * ks + g) ^ hcu) << 3)];
        #pragma unroll
        for (int nt = 0; nt < 4; nt++) hca[nt] = MFMA_BF16(a, wf[ks * 4 + nt], hca[nt]);
      }
    }
    #pragma unroll
    for (int mm = 0; mm < 4; mm++) {
      int m = 4 * w + mm;
      int vb = 16 * m + lm,  hb = swz8(vb);              // nbr row for this lane
      f32x4 a2[4];
      #pragma unroll
      for (int nt = 0; nt < 4; nt++)                     // init = hc + b_a1 (dedup'd)
        a2[nt] = f32x4{hca[nt][mm], hca[nt][mm], hca[nt][mm], hca[nt][mm]};
      #pragma unroll
      for (int ks = 0; ks < 2; ks++) {                   // nbr @ W_a1[64:128]
        bf16x8 a = *(const bf16x8*)&sE[vb * 64 + (((4 * ks + g) ^ hb) << 3)];
        #pragma unroll
        for (int nt = 0; nt < 4; nt++) a2[nt] = MFMA_BF16(a, wf[(2 + ks) * 4 + nt], a2[nt]);
      }
      float p[4];
      #pragma unroll
      for (int i = 0; i < 4; i++) {
        float acc = 0.f;
        #pragma unroll
        for (int nt = 0; nt < 4; nt++)
          acc = fmaf(fmaxf(a2[nt][i], 0.f), wa2v[nt], acc);
        p[i] = sum16(acc);                 // DPP reduce
      }
      const int4 mk = mkv[mm];
      float sc0 = mk.x ? p[0] : -1e30f, sc1 = mk.y ? p[1] : -1e30f;
      float sc2 = mk.z ? p[2] : -1e30f, sc3 = mk.w ? p[3] : -1e30f;
      float mloc = fmaxf(fmaxf(sc0, sc1), fmaxf(sc2, sc3));
      float mx = fmaxf(mloc, __shfl_xor(mloc, 16));   // partner g-half, same row
      float e0 = mk.x ? __expf(sc0 - mx) : 0.f;
      float e1 = mk.y ? __expf(sc1 - mx) : 0.f;
      float e2 = mk.z ? __expf(sc2 - mx) : 0.f;
      float e3 = mk.w ? __expf(sc3 - mx) : 0.f;
      float ss = (e0 + e1) + (e2 + e3);
      ss += __shfl_xor(ss, 16);
      float rinv = (ss > 0.f) ? (1.f / ss) : 0.f;     // all-masked row -> 0
      int r2 = 8 * w + 2 * mm + (g >> 1);
      if (lm == 0)
        *(float4*)(smem + 18432 + r2 * 128 + ((r2 & 3) << 5) + 16 * (g & 1)) =
            make_float4(e0 * rinv, e1 * rinv, e2 * rinv, e3 * rinv);
    }
    // Prefetch phase-O cur-half W_out frags + LN params (wf is dead now).
    #pragma unroll
    for (int f = 0; f < 8; f++) wof[f] = *(const bf16x8*)(woutf + (f * 64 + lane) * 8);
    #pragma unroll
    for (int nt = 0; nt < 4; nt++) {
      bovv[nt] = bout [16 * nt + lm];
      gvo[nt]  = gout [16 * nt + lm];
      bevo[nt] = beout[16 * nt + lm];
    }
  }
  __syncthreads();

  // ---------- Phase G: aggregate, thread = (row, 8-ch unit) ----------
  {
    int r = tid >> 3, cu = tid & 7;
    const char* sSr = smem + 18432 + r * 128 + ((r & 3) << 5);  // sS[r], in-wave RAW
    float4 wA = *(const float4*)sSr;
    float4 wB = *(const float4*)(sSr + 16);
    float wv[8] = {wA.x, wA.y, wA.z, wA.w, wB.x, wB.y, wB.z, wB.w};
    float a[8];
    #pragma unroll
    for (int e = 0; e < 8; e++) a[e] = 0.f;
    #pragma unroll
    for (int n = 0; n < 8; n++) {
      int v = 8 * r + n;
      u32x4 ev = *(const u32x4*)&sE[v * 64 + ((cu ^ swz8(v)) << 3)];
      float wn = wv[n];
      #pragma unroll
      for (int e2 = 0; e2 < 4; e2++) {
        unsigned int u = ev[e2];
        float lo = __builtin_bit_cast(float, u << 16);
        float hi = __builtin_bit_cast(float, u & 0xffff0000u);
        a[2 * e2]     = fmaf(wn, lo, a[2 * e2]);
        a[2 * e2 + 1] = fmaf(wn, hi, a[2 * e2 + 1]);
      }
    }
    // Overwrites sS[r] region -- safe: this wave's sS reads issued above.
    *(u32x4*)&sAgg[r * 64 + ((cu ^ swz8(r)) << 3)] =
        u32x4{pkbf2(a[0], a[1]), pkbf2(a[2], a[3]), pkbf2(a[4], a[5]), pkbf2(a[6], a[7])};
    // Prefetch agg-half W_out frags (in flight across the barrier).
    #pragma unroll
    for (int f = 0; f < 8; f++) wof[8 + f] = *(const bf16x8*)(woutf + ((8 + f) * 64 + lane) * 8);
  }
  __syncthreads();

  // ---------- Phase O: out-proj (K=128). Both waves compute ALL 4 nt tiles so the
  // 64-ch LN is fully in-register (in-lane adds + sum16 DPP) — no sLN LDS pass, no
  // 4th barrier. Wave w then stores ONLY nt = {2w, 2w+1}: full 64-lane dense store,
  // identical footprint to the proven pattern (wave0 ch 0..31, wave1 ch 32..63).
  {
    f32x4 acc[4];
    #pragma unroll
    for (int nt = 0; nt < 4; nt++)                       // b_out folded into MFMA C
      acc[nt] = f32x4{bovv[nt], bovv[nt], bovv[nt], bovv[nt]};
    const int vc = 128 + lm, hc = swz8(128 + lm);
    #pragma unroll
    for (int ks = 0; ks < 2; ks++) {
      bf16x8 a = *(const bf16x8*)&sE[vc * 64 + (((4 * ks + g) ^ hc) << 3)];
      #pragma unroll
      for (int nt = 0; nt < 4; nt++) acc[nt] = MFMA_BF16(a, wof[ks * 4 + nt], acc[nt]);
    }
    const int hA = swz8(lm);
    #pragma unroll
    for (int ks = 0; ks < 2; ks++) {
      bf16x8 a = *(const bf16x8*)&sAgg[lm * 64 + (((4 * ks + g) ^ hA) << 3)];
      #pragma unroll
      for (int nt = 0; nt < 4; nt++) acc[nt] = MFMA_BF16(a, wof[(2 + ks) * 4 + nt], acc[nt]);
    }
    float s1[4], s2[4];
    #pragma unroll
    for (int i = 0; i < 4; i++) {
      s1[i] = (acc[0][i] + acc[1][i]) + (acc[2][i] + acc[3][i]);
      s2[i] = fmaf(acc[0][i], acc[0][i], acc[1][i] * acc[1][i])
            + fmaf(acc[2][i], acc[2][i], acc[3][i] * acc[3][i]);
      s1[i] = sum16(s1[i]);                // DPP reduce across lm lanes
      s2[i] = sum16(s2[i]);
    }
    #pragma unroll
    for (int i = 0; i < 4; i++) {
      float mu = s1[i] * (1.f / 64.f);
      float rs = rsqrtf(s2[i] * (1.f / 64.f) - mu * mu + 1e-5f);
      size_t orow = (size_t)blk * 16 + 4 * g + i;
      #pragma unroll
      for (int j = 0; j < 2; j++) {
        int nt = 2 * w + j;
        float y = fmaxf(fmaf((acc[nt][i] - mu) * rs, gvo[nt], bevo[nt]), 0.f);
        out[orow * 64 + 16 * nt + lm] = y;   // all 64 lanes active: dense store
      }
    }
  }
}

// ---------------- launch ----------------
extern "C" void kernel_launch(void* const* d_in, const int* in_sizes, int n_in,
                              void* d_out, int out_size, void* d_ws, size_t ws_size,
                              hipStream_t stream) {
  const float* xcur = (const float*)d_in[0];   // [B,9]
  const float* xnbr = (const float*)d_in[1];   // [B,8,9]
  const int*   msk  = (const int*)  d_in[2];   // [B,8]
  const float* wenc = (const float*)d_in[3];
  const float* benc = (const float*)d_in[4];
  const float* genc = (const float*)d_in[5];
  const float* bee  = (const float*)d_in[6];
  const float* wa1  = (const float*)d_in[7];
  const float* ba1  = (const float*)d_in[8];
  const float* wa2  = (const float*)d_in[9];
  // d_in[10] = b_a2 (softmax-invariant, unused)
  const float* wout = (const float*)d_in[11];
  const float* bo   = (const float*)d_in[12];
  const float* go   = (const float*)d_in[13];
  const float* beo  = (const float*)d_in[14];

  unsigned short* wa1f  = (unsigned short*)d_ws;
  unsigned short* woutf = (unsigned short*)((char*)d_ws + 16384);
  unsigned short* wencT = (unsigned short*)((char*)d_ws + 32768);

  gcn_prep<<<20, 512, 0, stream>>>(wa1, wout, wenc, wa1f, woutf, wencT);
  gcn_main<<<8192, 128, 0, stream>>>(xcur, xnbr, msk, benc, genc, bee, ba1, wa2,
                                     bo, go, beo, wa1f, woutf, wencT, (float*)d_out);
}

// Round 6
// 65.829 us; speedup vs baseline: 1.1324x; 1.1324x over previous
//
#include <hip/hip_runtime.h>
#include <hip/hip_bf16.h>
#include <hip/hip_fp16.h>

// ---------------- types / helpers ----------------
typedef __attribute__((ext_vector_type(8))) short bf16x8;     // MFMA A/B frag (4 VGPR)
typedef __attribute__((ext_vector_type(4))) float f32x4;      // MFMA C/D frag
typedef __attribute__((ext_vector_type(2))) float f32x2;      // v_pk_*_f32 operand pair
typedef __attribute__((ext_vector_type(4))) unsigned int u32x4;
typedef __attribute__((ext_vector_type(2))) unsigned int u32x2;

#define MFMA_BF16(A,B,C) __builtin_amdgcn_mfma_f32_16x16x32_bf16((A),(B),(C),0,0,0)

static __device__ __forceinline__ unsigned int pkbf2(float a, float b) {
  __hip_bfloat162 h = __float22bfloat162_rn(make_float2(a, b));   // v_cvt_pk_bf16_f32
  unsigned int u; __builtin_memcpy(&u, &h, sizeof(u));
  return u;
}
static __device__ __forceinline__ unsigned short f2bf1(float f) {
  __hip_bfloat16 h = __float2bfloat16(f);
  unsigned short u; __builtin_memcpy(&u, &h, sizeof(u));
  return u;
}
// LDS 16B-unit swizzle hash (row bits 0..5 -> bank spread).
static __device__ __forceinline__ int swz8(int v) { return (v ^ (v >> 3)) & 7; }

// DPP row-rotate (within 16-lane row) — pure VALU, replaces ds_swizzle shuffles.
template<int N>
static __device__ __forceinline__ float rot16(float x) {
  return __builtin_bit_cast(float,
      __builtin_amdgcn_mov_dpp(__builtin_bit_cast(int, x), 0x120 + N, 0xF, 0xF, false));
}
// All-lane sum over the 16 lanes of a DPP row (lanes sharing lane>>4).
static __device__ __forceinline__ float sum16(float x) {
  x += rot16<8>(x);
  x += rot16<4>(x);
  x += rot16<2>(x);
  x += rot16<1>(x);
  return x;
}

// ---------------- d_ws layout (bytes) ----------------
// [    0,16384) : W_a1  bf16 B-frags [16 frag][64 lane][8 e]  frag f=kt*4+nt
// [16384,32768) : W_out bf16 B-frags same layout
// [32768,36864) : W_encT bf16 A-frags [4 mt][64 lane][8 e]  (k=8*(l>>4)+e, ch=16mt+(l&15); 0 for k>=9)
__global__ void gcn_prep(const float* __restrict__ wa1, const float* __restrict__ wout,
                         const float* __restrict__ wenc,
                         unsigned short* __restrict__ wa1f, unsigned short* __restrict__ woutf,
                         unsigned short* __restrict__ wencT) {
  int i = blockIdx.x * 512 + threadIdx.x;
  if (i < 8192) {
    int e = i & 7, l = (i >> 3) & 63, f = i >> 9;
    int kt = f >> 2, nt = f & 3;
    int k = 32 * kt + 8 * (l >> 4) + e;
    int col = 16 * nt + (l & 15);
    wa1f[i]  = f2bf1(wa1 [k * 64 + col]);
    woutf[i] = f2bf1(wout[k * 64 + col]);
  }
  int j = i - 8192;
  if (j >= 0 && j < 2048) {
    int e = j & 7, l = (j >> 3) & 63, mt = j >> 9;
    int k = 8 * (l >> 4) + e;
    int ch = 16 * mt + (l & 15);
    wencT[j] = (k < 9) ? f2bf1(wenc[k * 64 + ch]) : (unsigned short)0;
  }
}

// ---------------- fused main kernel ----------------
// 16 output rows / block, 128 threads (2 waves), grid 8192.
// LDS = 20480 B exactly -> 8 blocks/CU (163840/20480 = 8.0). 3 barriers total
// (E->S/G, G->O, O-internal sLN). The S->G barrier is REMOVED: after barrier 1
// sE is complete and read-only through G; sS[r] has reader wave == writer wave
// (r<8 <-> w0) and per-wave DS ops execute in order, so the RAW is in-wave.
// LDS map (byte offsets):
//   [    0,18432) sE   [144 vec][64 ch] bf16; 16B units swizzled: unit = c8 ^ swz8(v)
//                 vec 0..127 = nbr, 128..143 = cur (row r at 128+r)
//                 sLN (256 B, phase O only) overlays sE rows 0..1 (dead after G).
//   [18432,20480) sAgg [16 r][64 ch] bf16, swizzled like sE (written in G, read in O)
//                 sS[r] = 32 B f32 weights INSIDE sAgg row r at +((r&3)<<5):
//                 written in S, read at start of G (same wave as writer),
//                 then overwritten by the sAgg store (reads precede writes in-wave).
__global__ __launch_bounds__(128, 4) void gcn_main(
    const float* __restrict__ xcur, const float* __restrict__ xnbr,
    const int*   __restrict__ msk,
    const float* __restrict__ benc, const float* __restrict__ genc, const float* __restrict__ beenc,
    const float* __restrict__ ba1,  const float* __restrict__ wa2,
    const float* __restrict__ bout, const float* __restrict__ gout, const float* __restrict__ beout,
    const unsigned short* __restrict__ wa1f, const unsigned short* __restrict__ woutf,
    const unsigned short* __restrict__ wencT,
    float* __restrict__ out) {

  __shared__ __align__(16) char smem[20480];
  unsigned short* sE   = (unsigned short*)smem;
  unsigned short* sAgg = (unsigned short*)(smem + 18432);
  float*          sLN  = (float*)smem;                 // phase-O overlay on sE rows 0..1

  const int tid  = threadIdx.x;
  const int w    = tid >> 6;
  const int lane = tid & 63;
  const int lm   = lane & 15, g = lane >> 4;
  const int blk  = blockIdx.x;              // 16 output rows, 128 nbr vecs

  // Persisted across phases (prefetched early, used late):
  bf16x8 wf[16];                            // W_a1 frags (loaded before E->S barrier)
  bf16x8 wof[8];                            // W_out frags, this wave's nt pair (loaded in S)
  float bov[2], gvo[2], bevo[2];
  float ba1v[4], wa2v[4];
  int4 mkv[4];                              // masks for this wave's 4 score tiles

  // ---------- Phase E: encode 144 vecs via transposed MFMA (D[ch][vec]) ----------
  {
    bf16x8 ef[4];
    #pragma unroll
    for (int mt = 0; mt < 4; mt++) ef[mt] = *(const bf16x8*)(wencT + (mt * 64 + lane) * 8);
    f32x4 bv[4], gv[4], bev[4];
    #pragma unroll
    for (int mt = 0; mt < 4; mt++) {
      bv[mt]  = *(const f32x4*)(benc  + 16 * mt + 4 * g);
      gv[mt]  = *(const f32x4*)(genc  + 16 * mt + 4 * g);
      bev[mt] = *(const f32x4*)(beenc + 16 * mt + 4 * g);
    }
    #pragma unroll
    for (int nt = 0; nt < 4; nt++) { ba1v[nt] = ba1[16 * nt + lm]; wa2v[nt] = wa2[16 * nt + lm]; }
    // 2-deep x prefetch pipeline over this wave's tiles: t = w, w+2, ... (<=8)
    float nx[8];
    {
      const float* xb = (w < 8) ? (xnbr + ((size_t)blk * 128 + w * 16 + lm) * 9)
                                : (xcur + ((size_t)blk * 16 + lm) * 9);
      #pragma unroll
      for (int e = 0; e < 8; e++) nx[e] = 0.f;
      if (g == 0) {
        #pragma unroll
        for (int e = 0; e < 8; e++) nx[e] = xb[e];
      } else if (g == 1) nx[0] = xb[8];
    }
    #pragma unroll
    for (int s5 = 0; s5 < 5; s5++) {
      int t = 2 * s5 + w;
      if (t > 8) break;
      float xv[8];
      #pragma unroll
      for (int e = 0; e < 8; e++) xv[e] = nx[e];
      int tn = t + 2;
      if (tn <= 8) {                        // issue next tile's loads now
        const float* xb = (tn < 8) ? (xnbr + ((size_t)blk * 128 + tn * 16 + lm) * 9)
                                   : (xcur + ((size_t)blk * 16 + lm) * 9);
        #pragma unroll
        for (int e = 0; e < 8; e++) nx[e] = 0.f;
        if (g == 0) {
          #pragma unroll
          for (int e = 0; e < 8; e++) nx[e] = xb[e];
        } else if (g == 1) nx[0] = xb[8];
      }
      int v = (t < 8) ? (t * 16 + lm) : (128 + lm);
      u32x4 bq;
      #pragma unroll
      for (int e2 = 0; e2 < 4; e2++) bq[e2] = pkbf2(xv[2 * e2], xv[2 * e2 + 1]);
      bf16x8 bfr = __builtin_bit_cast(bf16x8, bq);
      f32x4 acc[4];
      #pragma unroll
      for (int mt = 0; mt < 4; mt++) acc[mt] = bv[mt];   // bias folded into MFMA C
      #pragma unroll
      for (int mt = 0; mt < 4; mt++) acc[mt] = MFMA_BF16(ef[mt], bfr, acc[mt]);
      // LN sums via packed-f32 (v_pk_add/v_pk_fma): acc pairs are adjacent VGPRs.
      f32x2 s1v = f32x2{0.f, 0.f}, s2v = f32x2{0.f, 0.f};
      #pragma unroll
      for (int mt = 0; mt < 4; mt++) {
        f32x2 lo; lo[0] = acc[mt][0]; lo[1] = acc[mt][1];
        f32x2 hi; hi[0] = acc[mt][2]; hi[1] = acc[mt][3];
        s1v += lo; s1v += hi;
        s2v = __builtin_elementwise_fma(lo, lo, s2v);
        s2v = __builtin_elementwise_fma(hi, hi, s2v);
      }
      float s1 = s1v[0] + s1v[1], s2 = s2v[0] + s2v[1];
      s1 += __shfl_xor(s1, 16); s1 += __shfl_xor(s1, 32);
      s2 += __shfl_xor(s2, 16); s2 += __shfl_xor(s2, 32);
      float mu = s1 * (1.f / 64.f);
      float rs = rsqrtf(s2 * (1.f / 64.f) - mu * mu + 1e-5f);
      float t0 = -mu * rs;                  // y = fma(fma(h, rs, t0), g, be): 3 ops/ch
      int h8 = swz8(v);
      #pragma unroll
      for (int mt = 0; mt < 4; mt++) {
        float y0 = fmaxf(fmaf(fmaf(acc[mt][0], rs, t0), gv[mt][0], bev[mt][0]), 0.f);
        float y1 = fmaxf(fmaf(fmaf(acc[mt][1], rs, t0), gv[mt][1], bev[mt][1]), 0.f);
        float y2 = fmaxf(fmaf(fmaf(acc[mt][2], rs, t0), gv[mt][2], bev[mt][2]), 0.f);
        float y3 = fmaxf(fmaf(fmaf(acc[mt][3], rs, t0), gv[mt][3], bev[mt][3]), 0.f);
        int unit = (2 * mt + (g >> 1)) ^ h8;
        *(u32x2*)&sE[v * 64 + unit * 8 + ((g & 1) << 2)] = u32x2{pkbf2(y0, y1), pkbf2(y2, y3)};
      }
    }
    // Prefetch phase-S operands so they are in flight across the barrier.
    #pragma unroll
    for (int f = 0; f < 16; f++) wf[f] = *(const bf16x8*)(wa1f + (f * 64 + lane) * 8);
    #pragma unroll
    for (int mm = 0; mm < 4; mm++) {
      int r2 = 8 * w + 2 * mm + (g >> 1);
      mkv[mm] = *(const int4*)(msk + ((size_t)(blk * 16 + r2)) * 8 + 4 * (g & 1));
    }
  }
  __syncthreads();

  // ---------- Phase S: scores + fused masked softmax -> sS weights ----------
  // hc dedup: cur@W_a1[0:64]+b_a1 is shared by all 8 neighbors of a row. Computed
  // ONCE per wave as a 16-row MFMA tile with pre-permuted A-rows so that lane
  // (g,lm)'s hca[nt][i] IS hc[8w + 2i + (g>>1)][16nt+lm] (score tile mm=i's init).
  {
    f32x4 hca[4];
    #pragma unroll
    for (int nt = 0; nt < 4; nt++)
      hca[nt] = f32x4{ba1v[nt], ba1v[nt], ba1v[nt], ba1v[nt]};
    {
      const int vcu = 128 + 8 * w + 2 * (lm & 3) + (lm >> 3), hcu = swz8(vcu);
      #pragma unroll
      for (int ks = 0; ks < 2; ks++) {                   // cur @ W_a1[0:64]
        bf16x8 a = *(const bf16x8*)&sE[vcu * 64 + (((4 * ks + g) ^ hcu) << 3)];
        #pragma unroll
        for (int nt = 0; nt < 4; nt++) hca[nt] = MFMA_BF16(a, wf[ks * 4 + nt], hca[nt]);
      }
    }
    #pragma unroll
    for (int mm = 0; mm < 4; mm++) {
      int m = 4 * w + mm;
      int vb = 16 * m + lm,  hb = swz8(vb);              // nbr row for this lane
      f32x4 a2[4];
      #pragma unroll
      for (int nt = 0; nt < 4; nt++)                     // init = hc + b_a1 (dedup'd)
        a2[nt] = f32x4{hca[nt][mm], hca[nt][mm], hca[nt][mm], hca[nt][mm]};
      #pragma unroll
      for (int ks = 0; ks < 2; ks++) {                   // nbr @ W_a1[64:128]
        bf16x8 a = *(const bf16x8*)&sE[vb * 64 + (((4 * ks + g) ^ hb) << 3)];
        #pragma unroll
        for (int nt = 0; nt < 4; nt++) a2[nt] = MFMA_BF16(a, wf[(2 + ks) * 4 + nt], a2[nt]);
      }
      float p[4];
      #pragma unroll
      for (int i = 0; i < 4; i++) {
        float acc = 0.f;
        #pragma unroll
        for (int nt = 0; nt < 4; nt++)
          acc = fmaf(fmaxf(a2[nt][i], 0.f), wa2v[nt], acc);
        p[i] = sum16(acc);                 // DPP reduce
      }
      const int4 mk = mkv[mm];
      float sc0 = mk.x ? p[0] : -1e30f, sc1 = mk.y ? p[1] : -1e30f;
      float sc2 = mk.z ? p[2] : -1e30f, sc3 = mk.w ? p[3] : -1e30f;
      float mloc = fmaxf(fmaxf(sc0, sc1), fmaxf(sc2, sc3));
      float mx = fmaxf(mloc, __shfl_xor(mloc, 16));   // partner g-half, same row
      float e0 = mk.x ? __expf(sc0 - mx) : 0.f;
      float e1 = mk.y ? __expf(sc1 - mx) : 0.f;
      float e2 = mk.z ? __expf(sc2 - mx) : 0.f;
      float e3 = mk.w ? __expf(sc3 - mx) : 0.f;
      float ss = (e0 + e1) + (e2 + e3);
      ss += __shfl_xor(ss, 16);
      float rinv = (ss > 0.f) ? (1.f / ss) : 0.f;     // all-masked row -> 0
      int r2 = 8 * w + 2 * mm + (g >> 1);
      if (lm == 0)
        *(float4*)(smem + 18432 + r2 * 128 + ((r2 & 3) << 5) + 16 * (g & 1)) =
            make_float4(e0 * rinv, e1 * rinv, e2 * rinv, e3 * rinv);
    }
    // Prefetch phase-O W_out frags (this wave's nt pair) + LN params (wf dead now).
    const int nt0 = 2 * w;
    #pragma unroll
    for (int kt = 0; kt < 4; kt++)
      #pragma unroll
      for (int j = 0; j < 2; j++)
        wof[kt * 2 + j] = *(const bf16x8*)(woutf + ((kt * 4 + nt0 + j) * 64 + lane) * 8);
    #pragma unroll
    for (int j = 0; j < 2; j++) {
      bov[j]  = bout [16 * (nt0 + j) + lm];
      gvo[j]  = gout [16 * (nt0 + j) + lm];
      bevo[j] = beout[16 * (nt0 + j) + lm];
    }
  }
  // NO barrier here: phase G reads only sE (stable since barrier 1) and this
  // wave's own sS rows (in-wave DS RAW: r = tid>>3 in [8w, 8w+8)).

  // ---------- Phase G: aggregate, thread = (row, 8-ch unit) ----------
  {
    int r = tid >> 3, cu = tid & 7;
    const char* sSr = smem + 18432 + r * 128 + ((r & 3) << 5);  // sS[r], in-wave RAW
    float4 wA = *(const float4*)sSr;
    float4 wB = *(const float4*)(sSr + 16);
    float wv[8] = {wA.x, wA.y, wA.z, wA.w, wB.x, wB.y, wB.z, wB.w};
    f32x2 av[4];
    #pragma unroll
    for (int e = 0; e < 4; e++) av[e] = f32x2{0.f, 0.f};
    #pragma unroll
    for (int n = 0; n < 8; n++) {
      int v = 8 * r + n;
      u32x4 ev = *(const u32x4*)&sE[v * 64 + ((cu ^ swz8(v)) << 3)];
      f32x2 wn2; wn2[0] = wv[n]; wn2[1] = wv[n];
      #pragma unroll
      for (int e2 = 0; e2 < 4; e2++) {       // {lo,hi} pair -> one v_pk_fma_f32
        unsigned int u = ev[e2];
        f32x2 lh;
        lh[0] = __builtin_bit_cast(float, u << 16);
        lh[1] = __builtin_bit_cast(float, u & 0xffff0000u);
        av[e2] = __builtin_elementwise_fma(wn2, lh, av[e2]);
      }
    }
    // Overwrites sS[r] region -- safe: this wave's sS reads issued above.
    *(u32x4*)&sAgg[r * 64 + ((cu ^ swz8(r)) << 3)] =
        u32x4{pkbf2(av[0][0], av[0][1]), pkbf2(av[1][0], av[1][1]),
              pkbf2(av[2][0], av[2][1]), pkbf2(av[3][0], av[3][1])};
  }
  __syncthreads();

  // ---------- Phase O: out-proj (K=128), wave w handles nt = {2w, 2w+1} ----------
  // FROZEN from round 3: exact store pattern + sLN + barrier (WRITE_SIZE == output).
  {
    const int nt0 = 2 * w;
    f32x4 acc[2];
    #pragma unroll
    for (int j = 0; j < 2; j++)                          // b_out folded into MFMA C
      acc[j] = f32x4{bov[j], bov[j], bov[j], bov[j]};
    const int vc = 128 + lm, hc = swz8(128 + lm);
    #pragma unroll
    for (int ks = 0; ks < 2; ks++) {
      bf16x8 a = *(const bf16x8*)&sE[vc * 64 + (((4 * ks + g) ^ hc) << 3)];
      #pragma unroll
      for (int j = 0; j < 2; j++) acc[j] = MFMA_BF16(a, wof[ks * 2 + j], acc[j]);
    }
    const int hA = swz8(lm);
    #pragma unroll
    for (int ks = 0; ks < 2; ks++) {
      bf16x8 a = *(const bf16x8*)&sAgg[lm * 64 + (((4 * ks + g) ^ hA) << 3)];
      #pragma unroll
      for (int j = 0; j < 2; j++) acc[j] = MFMA_BF16(a, wof[(2 + ks) * 2 + j], acc[j]);
    }
    float s1[4], s2[4];
    #pragma unroll
    for (int i = 0; i < 4; i++) {
      s1[i] = acc[0][i] + acc[1][i];
      s2[i] = fmaf(acc[0][i], acc[0][i], acc[1][i] * acc[1][i]);
      s1[i] = sum16(s1[i]);                // DPP reduce
      s2[i] = sum16(s2[i]);
    }
    if (lm == 0) {
      #pragma unroll
      for (int i = 0; i < 4; i++)
        *(float2*)&sLN[(4 * g + i) * 4 + 2 * w] = make_float2(s1[i], s2[i]);
    }
    __syncthreads();
    #pragma unroll
    for (int i = 0; i < 4; i++) {
      float2 pa = *(const float2*)&sLN[(4 * g + i) * 4];
      float2 pb = *(const float2*)&sLN[(4 * g + i) * 4 + 2];
      float S1 = pa.x + pb.x, S2 = pa.y + pb.y;
      float mu = S1 * (1.f / 64.f);
      float rs = rsqrtf(S2 * (1.f / 64.f) - mu * mu + 1e-5f);
      size_t orow = (size_t)blk * 16 + 4 * g + i;
      #pragma unroll
      for (int j = 0; j < 2; j++) {
        float y = fmaxf(fmaf((acc[j][i] - mu) * rs, gvo[j], bevo[j]), 0.f);
        out[orow * 64 + 16 * (nt0 + j) + lm] = y;
      }
    }
  }
}

// ---------------- launch ----------------
extern "C" void kernel_launch(void* const* d_in, const int* in_sizes, int n_in,
                              void* d_out, int out_size, void* d_ws, size_t ws_size,
                              hipStream_t stream) {
  const float* xcur = (const float*)d_in[0];   // [B,9]
  const float* xnbr = (const float*)d_in[1];   // [B,8,9]
  const int*   msk  = (const int*)  d_in[2];   // [B,8]
  const float* wenc = (const float*)d_in[3];
  const float* benc = (const float*)d_in[4];
  const float* genc = (const float*)d_in[5];
  const float* bee  = (const float*)d_in[6];
  const float* wa1  = (const float*)d_in[7];
  const float* ba1  = (const float*)d_in[8];
  const float* wa2  = (const float*)d_in[9];
  // d_in[10] = b_a2 (softmax-invariant, unused)
  const float* wout = (const float*)d_in[11];
  const float* bo   = (const float*)d_in[12];
  const float* go   = (const float*)d_in[13];
  const float* beo  = (const float*)d_in[14];

  unsigned short* wa1f  = (unsigned short*)d_ws;
  unsigned short* woutf = (unsigned short*)((char*)d_ws + 16384);
  unsigned short* wencT = (unsigned short*)((char*)d_ws + 32768);

  gcn_prep<<<20, 512, 0, stream>>>(wa1, wout, wenc, wa1f, woutf, wencT);
  gcn_main<<<8192, 128, 0, stream>>>(xcur, xnbr, msk, benc, genc, bee, ba1, wa2,
                                     bo, go, beo, wa1f, woutf, wencT, (float*)d_out);
}